// Round 14
// baseline (261.048 us; speedup 1.0000x reference)
//
#include <hip/hip_runtime.h>
#include <hip/hip_bf16.h>
#include <math.h>

#define LEN 128
#define NCH 8128             // chart rows 1..127 only (row 0 is provably zero)
#define TOTAL 349504
#define NCONSTR 8
#define BONUS 1000.0f
#define NT 512

// Barrier WITHOUT vmcnt drain (score prefetch stays in flight; T4 discipline).
__device__ __forceinline__ void level_barrier() {
    __builtin_amdgcn_sched_barrier(0);
    asm volatile("s_waitcnt lgkmcnt(0)\n\ts_barrier" ::: "memory");
    __builtin_amdgcn_sched_barrier(0);
}

__device__ __forceinline__ float dpp_xor1_max(float v) {
    int r = __builtin_amdgcn_update_dpp(0, __float_as_int(v), 0xB1, 0xF, 0xF, true);
    return fmaxf(v, __int_as_float(r));
}
__device__ __forceinline__ float dpp_xor2_max(float v) {
    int r = __builtin_amdgcn_update_dpp(0, __float_as_int(v), 0x4E, 0xF, 0xF, true);
    return fmaxf(v, __int_as_float(r));
}
template<int LG>
__device__ __forceinline__ void redmax(float& a) {
    #pragma unroll
    for (int mm = (1 << LG) >> 1; mm >= 4; mm >>= 1)
        a = fmaxf(a, __shfl_xor(a, mm));
    if constexpr (LG >= 2) a = dpp_xor2_max(a);
    if constexpr (LG >= 1) a = dpp_xor1_max(a);
}

__device__ __forceinline__ bool chit(int q, const int4 c0, const int4 c1) {
    return (q == c0.x) | (q == c0.y) | (q == c0.z) | (q == c0.w) |
           (q == c1.x) | (q == c1.y) | (q == c1.z) | (q == c1.w);
}

// One CKY level over a SINGLE chart stored WITHOUT row 0 (index - 128).
// Row-0 children are compile-/select-folded constants (0.0f). Bonus applied
// at write time via register compares -> no chart init, no RMW.
template<int LG, int LG2, int JM, int JM2>
__device__ __forceinline__ void lstep(const int level, int& soff,
        const float* __restrict__ g, float* __restrict__ ch,
        float (&rcur)[16], float (&rnxt)[16],
        const int4 cc0, const int4 cc1, const float kbonus, const int tid)
{
    const int N = level;
    const int L = LEN - level;
    constexpr int T = 1 << LG;
    const int pos = tid >> LG;
    const int sub = tid & (T - 1);
    const int soff_n = soff + L * N;

    // ---- issue next level's score loads (consumed after next barrier) ----
    if constexpr (LG2 >= 0) {
        constexpr int T2 = 1 << LG2;
        const int N2 = level + 1;
        const int L2 = L - 1;
        const int pos2 = tid >> LG2;
        const int sub2 = tid & (T2 - 1);
        if (pos2 < L2) {
            const float* __restrict__ gp = g + soff_n + pos2 * N2 + sub2;
            #pragma unroll
            for (int j = 0; j < JM2; j++) {
                if (sub2 + j * T2 < N2) rnxt[j] = gp[j * T2];
            }
        }
    }

    // ---- compute this level (phase-split: batch reads, then consume) ----
    float bp = -INFINITY;
    if (pos < L) {
        const int jml = (N - sub + T - 1) >> LG;   // per-lane valid trip count
        float lv[JM], rv[JM], xs[JM];
        #pragma unroll
        for (int j = 0; j < JM; j++) {
            const int n = sub + j * T;
            const int m = level - 1 - n;
            const bool v = (j < jml);
            const bool lok = (j > 0) || (n >= 1);          // row-0 left child -> 0
            int al = ((n * (257 - n)) >> 1) + pos - 128;
            al = lok ? al : 0;
            const bool rok = v && (m >= 1);                // row-0/invalid right -> 0
            int ar = ((m * (257 - m)) >> 1) + pos + n + 1 - 128;
            ar = rok ? ar : 0;
            const float lvj = ch[al];
            const float rvj = ch[ar];
            lv[j] = lok ? lvj : 0.f;
            rv[j] = rok ? rvj : 0.f;
            xs[j] = v ? rcur[j] : -INFINITY;
        }
        #pragma unroll
        for (int j = 0; j < JM; j++)
            bp = fmaxf(bp, lv[j] + rv[j] + xs[j]);
    }
    redmax<LG>(bp);
    if (pos < L && sub == 0) {
        const int q = ((level * (257 - level)) >> 1) + pos;   // row-major cell id
        ch[q - 128] = bp + (chit(q, cc0, cc1) ? kbonus : 0.f);
    }
    level_barrier();
    soff = soff_n;
}

// 4 levels at TPP=4, JM=K exactly (levels 4K-3..4K), double-buffered.
template<int K>
__device__ __forceinline__ void seg4(int& soff, const float* __restrict__ g,
        float* __restrict__ ch, float (&rA)[16], float (&rB)[16],
        const int4 cc0, const int4 cc1, const float kb, const int tid)
{
    const int l0 = 4 * K - 3;
    #pragma unroll 1
    for (int l = l0; l < l0 + 4; l += 2) {
        lstep<2, 2, K, K + 1>(l,     soff, g, ch, rA, rB, cc0, cc1, kb, tid);
        lstep<2, 2, K, K + 1>(l + 1, soff, g, ch, rB, rA, cc0, cc1, kb, tid);
    }
}

__global__ __launch_bounds__(NT)
void cky_kernel(const float* __restrict__ scores,
                const int* __restrict__ cpos,
                float* __restrict__ roots)
{
    __shared__ float ch[NCH];          // 32512 B -> two blocks fit a 64 KB window

    const int bb   = blockIdx.x;
    const int b    = bb & 255;         // batch element
    const int kind = bb >> 8;          // 0 = pred, 1 = constr (b, b+256: same XCD)
    const int tid  = threadIdx.x;
    const float* __restrict__ g = scores + (size_t)b * TOTAL;

    const int4* __restrict__ cp4 = (const int4*)(cpos + b * NCONSTR);
    const int4 cc0 = cp4[0];
    const int4 cc1 = cp4[1];
    const float kb = kind ? BONUS : 0.0f;

    float rA[16], rB[16];

    // ---- prefetch level 1 scores (N=1, TPP=4 mapping) ----
    {
        const int pos = tid >> 2;
        const int sub = tid & 3;
        if (pos < 127 && sub == 0) rA[0] = g[pos];
    }
    // NO chart init needed: row 0 is register-constant zero; every stored cell
    // is written before any barrier-separated read; stale-garbage reads are
    // masked by -INF terms (v_max drops NaN).
    level_barrier();

    int soff = 0;

    // ---- TPP=4: levels 1..60 via exact-JM segments ----
    seg4<1>(soff, g, ch, rA, rB, cc0, cc1, kb, tid);
    seg4<2>(soff, g, ch, rA, rB, cc0, cc1, kb, tid);
    seg4<3>(soff, g, ch, rA, rB, cc0, cc1, kb, tid);
    seg4<4>(soff, g, ch, rA, rB, cc0, cc1, kb, tid);
    seg4<5>(soff, g, ch, rA, rB, cc0, cc1, kb, tid);
    seg4<6>(soff, g, ch, rA, rB, cc0, cc1, kb, tid);
    seg4<7>(soff, g, ch, rA, rB, cc0, cc1, kb, tid);
    seg4<8>(soff, g, ch, rA, rB, cc0, cc1, kb, tid);
    seg4<9>(soff, g, ch, rA, rB, cc0, cc1, kb, tid);
    seg4<10>(soff, g, ch, rA, rB, cc0, cc1, kb, tid);
    seg4<11>(soff, g, ch, rA, rB, cc0, cc1, kb, tid);
    seg4<12>(soff, g, ch, rA, rB, cc0, cc1, kb, tid);
    seg4<13>(soff, g, ch, rA, rB, cc0, cc1, kb, tid);
    seg4<14>(soff, g, ch, rA, rB, cc0, cc1, kb, tid);
    seg4<15>(soff, g, ch, rA, rB, cc0, cc1, kb, tid);
    // ---- TPP=4 tail: levels 61..63 ----
    lstep<2,2,16,16>(61, soff, g, ch, rA, rB, cc0, cc1, kb, tid);
    lstep<2,2,16,16>(62, soff, g, ch, rB, rA, cc0, cc1, kb, tid);
    lstep<2,3,16,8> (63, soff, g, ch, rA, rB, cc0, cc1, kb, tid);   // next TPP=8
    // ---- TPP=8: levels 64..95 ----
    lstep<3,3,8,9>  (64, soff, g, ch, rB, rA, cc0, cc1, kb, tid);
    #pragma unroll 1
    for (int l = 65; l < 72; l += 2) {                   // 65..72 (JM=9)
        lstep<3,3,9,10>(l,     soff, g, ch, rA, rB, cc0, cc1, kb, tid);
        lstep<3,3,9,10>(l + 1, soff, g, ch, rB, rA, cc0, cc1, kb, tid);
    }
    #pragma unroll 1
    for (int l = 73; l < 80; l += 2) {                   // 73..80 (JM=10)
        lstep<3,3,10,11>(l,     soff, g, ch, rA, rB, cc0, cc1, kb, tid);
        lstep<3,3,10,11>(l + 1, soff, g, ch, rB, rA, cc0, cc1, kb, tid);
    }
    #pragma unroll 1
    for (int l = 81; l < 88; l += 2) {                   // 81..88 (JM=11)
        lstep<3,3,11,12>(l,     soff, g, ch, rA, rB, cc0, cc1, kb, tid);
        lstep<3,3,11,12>(l + 1, soff, g, ch, rB, rA, cc0, cc1, kb, tid);
    }
    #pragma unroll 1
    for (int l = 89; l < 94; l += 2) {                   // 89..94 (JM=12)
        lstep<3,3,12,12>(l,     soff, g, ch, rA, rB, cc0, cc1, kb, tid);
        lstep<3,3,12,12>(l + 1, soff, g, ch, rB, rA, cc0, cc1, kb, tid);
    }
    lstep<3,4,12,6> (95, soff, g, ch, rA, rB, cc0, cc1, kb, tid);   // next TPP=16
    // ---- TPP=16: levels 96..111 ----
    lstep<4,4,6,7>  (96, soff, g, ch, rB, rA, cc0, cc1, kb, tid);
    #pragma unroll 1
    for (int l = 97; l < 110; l += 2) {                  // 97..110 (JM=7)
        lstep<4,4,7,7>(l,     soff, g, ch, rA, rB, cc0, cc1, kb, tid);
        lstep<4,4,7,7>(l + 1, soff, g, ch, rB, rA, cc0, cc1, kb, tid);
    }
    lstep<4,5,7,4>(111, soff, g, ch, rA, rB, cc0, cc1, kb, tid);    // next TPP=32
    // ---- TPP=32: levels 112..119 ----
    lstep<5,5,4,4>(112, soff, g, ch, rB, rA, cc0, cc1, kb, tid);
    #pragma unroll 1
    for (int l = 113; l < 118; l += 2) {                 // 113..118
        lstep<5,5,4,4>(l,     soff, g, ch, rA, rB, cc0, cc1, kb, tid);
        lstep<5,5,4,4>(l + 1, soff, g, ch, rB, rA, cc0, cc1, kb, tid);
    }
    lstep<5,6,4,2>(119, soff, g, ch, rA, rB, cc0, cc1, kb, tid);    // next TPP=64
    // ---- TPP=64: levels 120..127 ----
    lstep<6,6,2,2>(120, soff, g, ch, rB, rA, cc0, cc1, kb, tid);
    #pragma unroll 1
    for (int l = 121; l < 126; l += 2) {                 // 121..126
        lstep<6,6,2,2>(l,     soff, g, ch, rA, rB, cc0, cc1, kb, tid);
        lstep<6,6,2,2>(l + 1, soff, g, ch, rB, rA, cc0, cc1, kb, tid);
    }
    lstep<6,-1,2,0>(127, soff, g, ch, rA, rB, cc0, cc1, kb, tid);   // root

    // ---- publish root; all 512 slots written every call ----
    if (tid == 0) roots[bb] = ch[NCH - 1];
}

__global__ __launch_bounds__(256)
void final_kernel(const float* __restrict__ roots, float* __restrict__ out) {
    const int t = threadIdx.x;                 // 0..255 = batch element
    const float pred   = roots[t];
    const float constr = roots[256 + t] - BONUS * NCONSTR;
    const float diff   = pred - constr;
    const float mask   = (fabsf(diff) >= 0.001f) ? 1.f : 0.f;
    float h = fmaxf(1.0f + diff, 0.f) * mask;
    float m = mask;
    #pragma unroll
    for (int s = 32; s > 0; s >>= 1) {
        h += __shfl_xor(h, s);
        m += __shfl_xor(m, s);
    }
    __shared__ float sh[8];
    const int w = t >> 6;
    if ((t & 63) == 0) { sh[w] = h; sh[4 + w] = m; }
    __syncthreads();
    if (t == 0) {
        const float H = sh[0] + sh[1] + sh[2] + sh[3];
        const float M = sh[4] + sh[5] + sh[6] + sh[7];
        out[0] = (M > 0.1f) ? (H / fmaxf(M, 1.f)) : H;
    }
}

extern "C" void kernel_launch(void* const* d_in, const int* in_sizes, int n_in,
                              void* d_out, int out_size, void* d_ws, size_t ws_size,
                              hipStream_t stream) {
    const float* scores = (const float*)d_in[0];
    const int*   cpos   = (const int*)d_in[1];
    float* out   = (float*)d_out;
    float* roots = (float*)d_ws;               // 512 floats

    cky_kernel<<<dim3(512), dim3(NT), 0, stream>>>(scores, cpos, roots);
    final_kernel<<<dim3(1), dim3(256), 0, stream>>>(roots, out);
}